// Round 9
// baseline (273.775 us; speedup 1.0000x reference)
//
#include <hip/hip_runtime.h>

// Shapes (fixed): B=64 H=16 T=4 Dk=128 Dv=256
#define BH 1024
#define TT 4
#define DK 128
#define DV 256
#define OUTOFF (BH * TT * DV)   // float offset of state region in out

// R9: two-phase pure-streaming decomposition.
// R8 post-mortem: five structurally different fused kernels all pin at
// ~2.5 TB/s while fillBuffer hits 6.6 TB/s in the same profile. The fused
// {read-state -> reduce/solve (no load issue) -> write-state} lifetime caps
// the per-CU load-issue duty cycle regardless of arrangement. Fix: split
// into two kernels whose inner loops are pure streams.
//   P1 (per bh): read S0 once, c_t=S0^T k_t, p_t=S0^T q_t, Gram scalars,
//       triangular solve -> write o (4MB) and d (4MB workspace).
//   P2: S4 = G3*S0 + sum_t W_t k_t (x) d_t  -- a copy with 4 fma/element,
//       no barriers/LDS, 16 independent 1KB rows per wave.
// Cost: S0 read twice (+128MB). Bet: streaming shape buys >2x BW.

#define FMA4(acc, s, kk) \
    acc.x = fmaf(s.x, kk, acc.x); acc.y = fmaf(s.y, kk, acc.y); \
    acc.z = fmaf(s.z, kk, acc.z); acc.w = fmaf(s.w, kk, acc.w)

__global__ __launch_bounds__(256)
void p1_readout(const float* __restrict__ q, const float* __restrict__ k,
                const float* __restrict__ v, const float* __restrict__ g,
                const float* __restrict__ beta, const float* __restrict__ s0,
                float* __restrict__ out, float* __restrict__ dws)
{
    const int bh  = blockIdx.x;
    const int tid = threadIdx.x;
    const int rg  = tid >> 6;          // wave = row-group, rows [32rg,32rg+32)
    const int l   = tid & 63;
    const int cq  = l << 2;            // float4 col base (wave covers full 1KB row)

    const float* __restrict__ kb = k  + (size_t)bh * TT * DK;
    const float* __restrict__ qb = q  + (size_t)bh * TT * DK;
    const float* __restrict__ vb = v  + (size_t)bh * TT * DV;
    const float* __restrict__ sp = s0 + (size_t)bh * DK * DV;
    float* __restrict__ out_p = out + (size_t)bh * TT * DV;
    float* __restrict__ d_p   = dws + (size_t)bh * TT * DV;

    __shared__ __align__(16) float ksh[DK][4];       // [row][t]
    __shared__ __align__(16) float qsh[DK][4];
    __shared__ __align__(16) float redc[TT][4][DV];  // c partials per row-group
    __shared__ __align__(16) float redp[TT][4][DV];  // p partials

    // k/q staging loads first (retire first), v + g/beta for the solve stage
    const int e0 = tid, e1 = tid + 256;
    const float kl0 = kb[e0], kl1 = kb[e1];
    const float ql0 = qb[e0], ql1 = qb[e1];
    float vv[TT];
#pragma unroll
    for (int t = 0; t < TT; ++t) vv[t] = vb[t * DV + tid];   // thread = col
    const float4 gq = *(const float4*)(g    + (size_t)bh * TT);
    const float4 bq = *(const float4*)(beta + (size_t)bh * TT);

    ksh[e0 & 127][e0 >> 7] = kl0;
    ksh[e1 & 127][e1 >> 7] = kl1;
    qsh[e0 & 127][e0 >> 7] = ql0;
    qsh[e1 & 127][e1 >> 7] = ql1;
    __syncthreads();                                  // B0: ksh/qsh visible

    // ---- Gram scalars (per-wave 64-lane butterfly, wave-redundant) ----
    const float4 kA = *(const float4*)&ksh[l][0];
    const float4 kB = *(const float4*)&ksh[l + 64][0];
    const float4 qA = *(const float4*)&qsh[l][0];
    const float4 qB = *(const float4*)&qsh[l + 64][0];
    const float a0[4] = {kA.x, kA.y, kA.z, kA.w};
    const float a1[4] = {kB.x, kB.y, kB.z, kB.w};
    const float b0[4] = {qA.x, qA.y, qA.z, qA.w};
    const float b1[4] = {qB.x, qB.y, qB.z, qB.w};
    float AA[4][4], BB[4][4];
#pragma unroll
    for (int s = 0; s < 4; ++s) {
#pragma unroll
        for (int t = 0; t < 4; ++t) {
            if (t > s) {
                float x = fmaf(a1[s], a1[t], a0[s] * a0[t]);
#pragma unroll
                for (int m = 1; m < 64; m <<= 1) x += __shfl_xor(x, m);
                AA[s][t] = x;
            }
            if (t >= s) {
                float x = fmaf(a1[s], b1[t], a0[s] * b0[t]);
#pragma unroll
                for (int m = 1; m < 64; m <<= 1) x += __shfl_xor(x, m);
                BB[s][t] = x;
            }
        }
    }

    // ---- pure read stream: 32 full-row float4 loads, c/p accumulation ----
    float4 c4[TT] = {{0,0,0,0},{0,0,0,0},{0,0,0,0},{0,0,0,0}};
    float4 p4[TT] = {{0,0,0,0},{0,0,0,0},{0,0,0,0},{0,0,0,0}};
#pragma unroll
    for (int i = 0; i < 32; ++i) {
        const int r = rg * 32 + i;
        const float4 s  = *(const float4*)&sp[(size_t)r * DV + cq];
        const float4 k4 = *(const float4*)&ksh[r][0];   // broadcast
        const float4 q4 = *(const float4*)&qsh[r][0];   // broadcast
        FMA4(c4[0], s, k4.x); FMA4(c4[1], s, k4.y);
        FMA4(c4[2], s, k4.z); FMA4(c4[3], s, k4.w);
        FMA4(p4[0], s, q4.x); FMA4(p4[1], s, q4.y);
        FMA4(p4[2], s, q4.z); FMA4(p4[3], s, q4.w);
    }
#pragma unroll
    for (int t = 0; t < TT; ++t) {
        *(float4*)&redc[t][rg][cq] = c4[t];
        *(float4*)&redp[t][rg][cq] = p4[t];
    }
    __syncthreads();                                  // B1: partials visible

    // ---- solve stage: thread = col ----
    const int col = tid;
    float cc[TT], pp[TT];
#pragma unroll
    for (int t = 0; t < TT; ++t) {
        cc[t] = (redc[t][0][col] + redc[t][1][col]) + (redc[t][2][col] + redc[t][3][col]);
        pp[t] = (redp[t][0][col] + redp[t][1][col]) + (redp[t][2][col] + redp[t][3][col]);
    }
    const float y0 = expf(gq.x), y1 = expf(gq.y), y2 = expf(gq.z), y3 = expf(gq.w);
    const float G0 = y0, G1 = y0*y1, G2 = y0*y1*y2, G3 = y0*y1*y2*y3;
    const float M01 = y1, M02 = y1*y2, M03 = y1*y2*y3;
    const float M12 = y2, M13 = y2*y3, M23 = y3;

    float d0, d1, d2, d3;
    d0 = bq.x * (vv[0] - G0 * cc[0]);
    d1 = bq.y * (vv[1] - G1 * cc[1] - M01 * AA[0][1] * d0);
    d2 = bq.z * (vv[2] - G2 * cc[2] - M02 * AA[0][2] * d0 - M12 * AA[1][2] * d1);
    d3 = bq.w * (vv[3] - G3 * cc[3] - M03 * AA[0][3] * d0 - M13 * AA[1][3] * d1
                                     - M23 * AA[2][3] * d2);

    float o0 = fmaf(BB[0][0], d0, G0 * pp[0]);
    float o1 = G1 * pp[1];
    o1 = fmaf(M01 * BB[0][1], d0, o1);
    o1 = fmaf(BB[1][1], d1, o1);
    float o2 = G2 * pp[2];
    o2 = fmaf(M02 * BB[0][2], d0, o2);
    o2 = fmaf(M12 * BB[1][2], d1, o2);
    o2 = fmaf(BB[2][2], d2, o2);
    float o3 = G3 * pp[3];
    o3 = fmaf(M03 * BB[0][3], d0, o3);
    o3 = fmaf(M13 * BB[1][3], d1, o3);
    o3 = fmaf(M23 * BB[2][3], d2, o3);
    o3 = fmaf(BB[3][3], d3, o3);

    out_p[0 * DV + col] = o0;  out_p[1 * DV + col] = o1;
    out_p[2 * DV + col] = o2;  out_p[3 * DV + col] = o3;
    d_p[0 * DV + col] = d0;    d_p[1 * DV + col] = d1;
    d_p[2 * DV + col] = d2;    d_p[3 * DV + col] = d3;
}

// P2: S4 = G3*S0 + sum_t W_t k_t (x) d_t  -- copy-shaped, no LDS/barriers.
// 2048 blocks x 4 waves = 8192 waves; wave gw: bh = gw>>3, rows [16*(gw&7), +16).
__global__ __launch_bounds__(256)
void p2_update(const float* __restrict__ k, const float* __restrict__ g,
               const float* __restrict__ s0, const float* __restrict__ dws,
               float* __restrict__ out)
{
    const int gw = blockIdx.x * 4 + (threadIdx.x >> 6);
    const int bh = gw >> 3;
    const int r0 = (gw & 7) << 4;
    const int cq = (threadIdx.x & 63) << 2;

    const float4 gq = *(const float4*)(g + (size_t)bh * TT);
    const float y1 = expf(gq.y), y2 = expf(gq.z), y3 = expf(gq.w);
    const float y0 = expf(gq.x);
    const float G3 = y0 * y1 * y2 * y3;
    const float W0 = y1 * y2 * y3, W1 = y2 * y3, W2 = y3;

    const float* __restrict__ dd = dws + (size_t)bh * TT * DV;
    const float4 d0 = *(const float4*)&dd[0 * DV + cq];
    const float4 d1 = *(const float4*)&dd[1 * DV + cq];
    const float4 d2 = *(const float4*)&dd[2 * DV + cq];
    const float4 d3 = *(const float4*)&dd[3 * DV + cq];

    const float* __restrict__ kb = k + (size_t)bh * TT * DK;
    const float* __restrict__ sp = s0 + (size_t)bh * DK * DV;
    float* __restrict__ so = out + (size_t)OUTOFF + (size_t)bh * DK * DV;

#pragma unroll
    for (int i = 0; i < 16; ++i) {
        const int r = r0 + i;
        // wave-uniform k reads (scalar-cached)
        const float h0 = W0 * kb[0 * DK + r];
        const float h1 = W1 * kb[1 * DK + r];
        const float h2 = W2 * kb[2 * DK + r];
        const float h3 =      kb[3 * DK + r];
        const float4 s = *(const float4*)&sp[(size_t)r * DV + cq];
        float4 o;
        o.x = fmaf(h0, d0.x, fmaf(h1, d1.x, fmaf(h2, d2.x, fmaf(h3, d3.x, s.x * G3))));
        o.y = fmaf(h0, d0.y, fmaf(h1, d1.y, fmaf(h2, d2.y, fmaf(h3, d3.y, s.y * G3))));
        o.z = fmaf(h0, d0.z, fmaf(h1, d1.z, fmaf(h2, d2.z, fmaf(h3, d3.z, s.z * G3))));
        o.w = fmaf(h0, d0.w, fmaf(h1, d1.w, fmaf(h2, d2.w, fmaf(h3, d3.w, s.w * G3))));
        *(float4*)&so[(size_t)r * DV + cq] = o;
    }
}

extern "C" void kernel_launch(void* const* d_in, const int* in_sizes, int n_in,
                              void* d_out, int out_size, void* d_ws, size_t ws_size,
                              hipStream_t stream) {
    const float* q    = (const float*)d_in[0];
    const float* k    = (const float*)d_in[1];
    const float* v    = (const float*)d_in[2];
    const float* g    = (const float*)d_in[3];
    const float* beta = (const float*)d_in[4];
    const float* s0   = (const float*)d_in[5];
    float* out = (float*)d_out;
    float* dws = (float*)d_ws;     // needs BH*TT*DV*4 = 4 MB of workspace

    p1_readout<<<dim3(BH), dim3(256), 0, stream>>>(q, k, v, g, beta, s0, out, dws);
    p2_update <<<dim3(2048), dim3(256), 0, stream>>>(k, g, s0, dws, out);
}